// Round 3
// baseline (112.781 us; speedup 1.0000x reference)
//
#include <hip/hip_runtime.h>
#include <hip/hip_bf16.h>
#include <math.h>

#define NFEAT 16
#define NRULE 64
#define RSTRIDE 52   // floats per rule block (13 x float4)
#define RPW 16       // rules per wave
#define WPB 4        // waves per block = NRULE / RPW

// Packed constant layout per rule r (floats, base = CST + r*RSTRIDE):
//   [0:16)  negc[a]  = -log2(e)/(2*sigma^2)
//   [16:32) cmu2[a]  =  log2(e)*mu/sigma^2
//   [32:48) rho_a[a] =  rho[r][a]
//   [48]    bias     =  rho[r][A]
//   [49]    K        = -log2(e)*sum_a mu^2/(2*sigma^2)
//   [50:52) pad
// Gaussian terms are pre-scaled by log2(e) so w = exp2(l) = one v_exp_f32.
__constant__ float CST[NRULE * RSTRIDE];

__global__ void fuzzy_prep(const float* __restrict__ mu,
                           const float* __restrict__ sigma,
                           const float* __restrict__ rho,
                           float* __restrict__ cst) {
    const float L2E = 1.4426950408889634f;
    int r = threadIdx.x;
    if (r >= NRULE) return;
    float* c = cst + r * RSTRIDE;
    float K = 0.0f;
#pragma unroll
    for (int a = 0; a < NFEAT; ++a) {
        float m = mu[r * NFEAT + a];
        float s = sigma[r * NFEAT + a];
        float inv = 1.0f / (2.0f * s * s);
        c[a]      = -inv * L2E;
        c[16 + a] = 2.0f * inv * m * L2E;
        c[32 + a] = rho[r * (NFEAT + 1) + a];
        K         = fmaf(-inv * m, m, K);
    }
    c[48] = rho[r * (NFEAT + 1) + NFEAT];
    c[49] = K * L2E;
    c[50] = 0.0f;
    c[51] = 0.0f;
}

// Block = 256 threads = 4 waves; block covers 64 samples.
// Wave q computes rules [16q, 16q+16) for all 64 samples (sample = lane),
// then LDS-reduce the 4 partial (num, den) pairs.
__global__ __launch_bounds__(256) void fuzzy_main(const float* __restrict__ x,
                                                  float* __restrict__ out,
                                                  int n) {
    int lane = threadIdx.x & 63;
    int q    = threadIdx.x >> 6;
    int k    = blockIdx.x * 64 + lane;
    int kc   = k < n ? k : n - 1;   // clamp for safe loads (N % 64 == 0 anyway)

    const float4* x4 = (const float4*)(x + (size_t)kc * NFEAT);
    float4 v0 = x4[0], v1 = x4[1], v2 = x4[2], v3 = x4[3];
    float xs[NFEAT] = {v0.x, v0.y, v0.z, v0.w,
                       v1.x, v1.y, v1.z, v1.w,
                       v2.x, v2.y, v2.z, v2.w,
                       v3.x, v3.y, v3.z, v3.w};
    float xq[NFEAT];
#pragma unroll
    for (int a = 0; a < NFEAT; ++a) xq[a] = xs[a] * xs[a];

    float num = 0.0f, den = 0.0f;
    const float* cbase = CST + q * RPW * RSTRIDE;
#pragma unroll 4
    for (int r = 0; r < RPW; ++r) {
        const float* c = cbase + r * RSTRIDE;   // wave-uniform -> s_load
        float z  = c[48];
        float l0 = c[49];
        float l1 = 0.0f;
#pragma unroll
        for (int a = 0; a < NFEAT; ++a) {
            z  = fmaf(c[32 + a], xs[a], z);
            l0 = fmaf(c[a],      xq[a], l0);
            l1 = fmaf(c[16 + a], xs[a], l1);
        }
        float w = __builtin_amdgcn_exp2f(l0 + l1);  // one v_exp_f32
        num = fmaf(z, w, num);
        den += w;
    }

    __shared__ float pnum[WPB][64];
    __shared__ float pden[WPB][64];
    pnum[q][lane] = num;
    pden[q][lane] = den;
    __syncthreads();
    if (q == 0 && k < n) {
        float nn = pnum[0][lane] + pnum[1][lane] + pnum[2][lane] + pnum[3][lane];
        float dd = pden[0][lane] + pden[1][lane] + pden[2][lane] + pden[3][lane];
        out[k] = nn / (dd + 1e-13f);
    }
}

extern "C" void kernel_launch(void* const* d_in, const int* in_sizes, int n_in,
                              void* d_out, int out_size, void* d_ws, size_t ws_size,
                              hipStream_t stream) {
    const float* x     = (const float*)d_in[0];   // [N,16]
    const float* mu    = (const float*)d_in[1];   // [64,16]
    const float* sigma = (const float*)d_in[2];   // [64,16]
    const float* rho   = (const float*)d_in[3];   // [64,17]
    float* out = (float*)d_out;

    int n = in_sizes[0] / NFEAT;                  // 131072

    void* cst_dev = nullptr;
    (void)hipGetSymbolAddress(&cst_dev, HIP_SYMBOL(CST));

    fuzzy_prep<<<1, 64, 0, stream>>>(mu, sigma, rho, (float*)cst_dev);
    fuzzy_main<<<(n + 63) / 64, 256, 0, stream>>>(x, out, n);
}

// Round 5
// 75.448 us; speedup vs baseline: 1.4948x; 1.4948x over previous
//
#include <hip/hip_runtime.h>
#include <hip/hip_bf16.h>
#include <math.h>

#define NFEAT 16
#define NRULE 64
#define RSTRIDE 52   // floats per rule block (13 x float4)
#define RPW 16       // rules per wave
#define WPB 4        // waves per block = NRULE / RPW

// Packed constant layout per rule r (floats, base = CST + r*RSTRIDE):
//   [0:16)  negc[a]  = -log2(e)/(2*sigma^2)
//   [16:32) cmu2[a]  =  log2(e)*mu/sigma^2
//   [32:48) rho_a[a] =  rho[r][a]
//   [48]    bias     =  rho[r][A]
//   [49]    K        = -log2(e)*sum_a mu^2/(2*sigma^2)
//   [50:52) pad
// Gaussian terms pre-scaled by log2(e): w = exp2(l) = one v_exp_f32.
//
// __constant__ + PROVABLY uniform index (q via readfirstlane) ->
// s_load_dwordx* through the scalar cache: the only free broadcast path.
// (R3 lesson: q = tid>>6 alone is NOT provably uniform; SGPR_Count fell
// 112->16 and constants became per-lane VMEM broadcasts.)
__constant__ float CST[NRULE * RSTRIDE];

__global__ void fuzzy_prep(const float* __restrict__ mu,
                           const float* __restrict__ sigma,
                           const float* __restrict__ rho,
                           float* __restrict__ cst) {
    const float L2E = 1.4426950408889634f;
    int r = threadIdx.x;
    if (r >= NRULE) return;
    float* c = cst + r * RSTRIDE;
    float K = 0.0f;
#pragma unroll
    for (int a = 0; a < NFEAT; ++a) {
        float m = mu[r * NFEAT + a];
        float s = sigma[r * NFEAT + a];
        float inv = 1.0f / (2.0f * s * s);
        c[a]      = -inv * L2E;
        c[16 + a] = 2.0f * inv * m * L2E;
        c[32 + a] = rho[r * (NFEAT + 1) + a];
        K         = fmaf(-inv * m, m, K);
    }
    c[48] = rho[r * (NFEAT + 1) + NFEAT];
    c[49] = K * L2E;
    c[50] = 0.0f;
    c[51] = 0.0f;
}

// Block = 256 threads = 4 waves; block covers 64 samples (sample = lane).
// Wave q computes rules [16q, 16q+16) for all 64 samples, then a 2 KB LDS
// reduction combines the 4 partial (num, den) pairs.
__global__ __launch_bounds__(256) void fuzzy_main(const float* __restrict__ x,
                                                  float* __restrict__ out,
                                                  int n) {
    int lane = threadIdx.x & 63;
    int q    = __builtin_amdgcn_readfirstlane(threadIdx.x >> 6); // uniform!
    int k    = blockIdx.x * 64 + lane;
    int kc   = k < n ? k : n - 1;   // clamp (N % 64 == 0 anyway)

    // 16 features per sample: 4 x float4, 64 B/thread, coalesced.
    const float4* x4 = (const float4*)(x + (size_t)kc * NFEAT);
    float4 v0 = x4[0], v1 = x4[1], v2 = x4[2], v3 = x4[3];
    float xs[NFEAT] = {v0.x, v0.y, v0.z, v0.w,
                       v1.x, v1.y, v1.z, v1.w,
                       v2.x, v2.y, v2.z, v2.w,
                       v3.x, v3.y, v3.z, v3.w};
    float xq[NFEAT];
#pragma unroll
    for (int a = 0; a < NFEAT; ++a) xq[a] = xs[a] * xs[a];

    float num = 0.0f, den = 0.0f;
    const float* cbase = CST + q * (RPW * RSTRIDE);  // uniform -> s_load
#pragma unroll 4
    for (int r = 0; r < RPW; ++r) {
        const float* c = cbase + r * RSTRIDE;
        float z  = c[48];
        float l0 = c[49];
        float l1 = 0.0f;
#pragma unroll
        for (int a = 0; a < NFEAT; ++a) {
            z  = fmaf(c[32 + a], xs[a], z);   // VOP3: 1 SGPR + 1 VGPR operand
            l0 = fmaf(c[a],      xq[a], l0);
            l1 = fmaf(c[16 + a], xs[a], l1);
        }
        float w = __builtin_amdgcn_exp2f(l0 + l1);  // one v_exp_f32
        num = fmaf(z, w, num);
        den += w;
    }

    __shared__ float pnum[WPB][64];
    __shared__ float pden[WPB][64];
    pnum[q][lane] = num;
    pden[q][lane] = den;
    __syncthreads();
    if (q == 0 && k < n) {
        float nn = pnum[0][lane] + pnum[1][lane] + pnum[2][lane] + pnum[3][lane];
        float dd = pden[0][lane] + pden[1][lane] + pden[2][lane] + pden[3][lane];
        out[k] = nn / (dd + 1e-13f);
    }
}

extern "C" void kernel_launch(void* const* d_in, const int* in_sizes, int n_in,
                              void* d_out, int out_size, void* d_ws, size_t ws_size,
                              hipStream_t stream) {
    const float* x     = (const float*)d_in[0];   // [N,16]
    const float* mu    = (const float*)d_in[1];   // [64,16]
    const float* sigma = (const float*)d_in[2];   // [64,16]
    const float* rho   = (const float*)d_in[3];   // [64,17]
    float* out = (float*)d_out;

    int n = in_sizes[0] / NFEAT;                  // 131072

    void* cst_dev = nullptr;
    (void)hipGetSymbolAddress(&cst_dev, HIP_SYMBOL(CST));

    fuzzy_prep<<<1, 64, 0, stream>>>(mu, sigma, rho, (float*)cst_dev);
    fuzzy_main<<<(n + 63) / 64, 256, 0, stream>>>(x, out, n);
}